// Round 1
// baseline (2992.002 us; speedup 1.0000x reference)
//
#include <hip/hip_runtime.h>
#include <math.h>

// DCRNN (1 step, H0=0) + GCN + BN + Linear for N=50000, F=32, H=64, K=3, E=800000.
//
// Key algebra: H0 == 0  =>  R gate (Wr,br) is unused; hidden half of XH is zero
// through all diffusion hops (propagation is linear), so only W[:, :, :32, :]
// contributes.  F = [x, To1, Ti1, To2, Ti2]  (N x 160),
//   Zpre = F @ WcZ + bz,  Hpre = F @ WcH + bh,  H = (1 - sigmoid(Zpre)) * tanh(Hpre)
// with WcZ rows: [Wz[0,0]+Wz[1,0]; Wz[0,1]; Wz[1,1]; Wz[0,2]; Wz[1,2]] (each [:32,:]).

#define BN_EPS 1e-5f

// ---------------- degree accumulation (weighted out/in + unweighted gcn) ---------
__global__ void k_deg(const int* __restrict__ row, const int* __restrict__ col,
                      const float* __restrict__ ew,
                      float* __restrict__ deg_out, float* __restrict__ deg_in,
                      float* __restrict__ deg_gcn, int E) {
    int e = blockIdx.x * blockDim.x + threadIdx.x;
    if (e >= E) return;
    float w = ew[e];
    atomicAdd(&deg_out[row[e]], w);
    atomicAdd(&deg_in[col[e]], w);
    atomicAdd(&deg_gcn[col[e]], 1.0f);
}

// per-edge normalized weights w_out = ew/deg_out[row], w_in = ew/deg_in[col]
__global__ void k_edge_w(const int* __restrict__ row, const int* __restrict__ col,
                         const float* __restrict__ ew,
                         const float* __restrict__ deg_out, const float* __restrict__ deg_in,
                         float* __restrict__ w_out, float* __restrict__ w_in, int E) {
    int e = blockIdx.x * blockDim.x + threadIdx.x;
    if (e >= E) return;
    float w  = ew[e];
    float dO = deg_out[row[e]];
    float dI = deg_in[col[e]];
    w_out[e] = dO > 0.f ? w / dO : 0.f;
    w_in[e]  = dI > 0.f ? w / dI : 0.f;
}

// dis[i] = rsqrt(deg_gcn[i] + 1)   (+1 = self loop)
__global__ void k_dis(const float* __restrict__ deg_gcn, float* __restrict__ dis, int N) {
    int i = blockIdx.x * blockDim.x + threadIdx.x;
    if (i >= N) return;
    dis[i] = rsqrtf(deg_gcn[i] + 1.0f);
}

// one diffusion hop, both directions in one launch.
// out-dir: Do[col] += w_out[e]*So[row];  in-dir: Di[row] += w_in[e]*Si[col]
// thread t: f = t&31 (feature), p = t>>5 in [0, 2E)
__global__ void k_hop(const int* __restrict__ row, const int* __restrict__ col,
                      const float* __restrict__ w_out, const float* __restrict__ w_in,
                      const float* __restrict__ So, const float* __restrict__ Si,
                      float* __restrict__ Do, float* __restrict__ Di, int E) {
    int t = blockIdx.x * blockDim.x + threadIdx.x;
    if (t >= E * 64) return;                 // 2 dirs * 32 feats
    int f = t & 31;
    int p = t >> 5;
    if (p < E) {
        int e = p;
        atomicAdd(&Do[col[e] * 32 + f], w_out[e] * So[row[e] * 32 + f]);
    } else {
        int e = p - E;
        atomicAdd(&Di[row[e] * 32 + f], w_in[e] * Si[col[e] * 32 + f]);
    }
}

// fills lds[160*64] with the combined dconv weight built from W (2,3,96,64), rows [:32]
__device__ inline void fill_comb_w(float* lds, const float* __restrict__ W, int tid, int bdim) {
    for (int idx = tid; idx < 160 * 64; idx += bdim) {
        int rr = idx >> 6, c = idx & 63;
        int blk = rr >> 5, r = rr & 31;
        float v;
        if (blk == 0) {
            v = W[r * 64 + c] + W[(3 * 96 + r) * 64 + c];           // W[0,0]+W[1,0]
        } else {
            int k = (blk + 1) >> 1;                                  // 1,1,2,2
            int d = (blk + 1) & 1;                                   // 0,1,0,1
            v = W[((d * 3 + k) * 96 + r) * 64 + c];
        }
        lds[idx] = v;
    }
}

// Z = sigmoid(F @ WcZ + bz).  wave = 4 nodes, lane = output channel.
__global__ __launch_bounds__(256) void k_z(
    const float* __restrict__ x, const float* __restrict__ txo1,
    const float* __restrict__ txi1, const float* __restrict__ txo2,
    const float* __restrict__ txi2,
    const float* __restrict__ Wz, const float* __restrict__ bz,
    float* __restrict__ Z, int N) {
    __shared__ float wl[160 * 64];                 // 40 KB
    fill_comb_w(wl, Wz, threadIdx.x, blockDim.x);
    __syncthreads();
    int lane = threadIdx.x & 63;
    int wave = (blockIdx.x * blockDim.x + threadIdx.x) >> 6;
    int nwaves = (gridDim.x * blockDim.x) >> 6;
    float bl = bz[lane];
    const float* F[5] = {x, txo1, txi1, txo2, txi2};
    for (int i0 = wave * 4; i0 < N; i0 += nwaves * 4) {
        float acc[4] = {0.f, 0.f, 0.f, 0.f};
        for (int b = 0; b < 5; ++b) {
            const float4* fr[4];
            for (int n = 0; n < 4; ++n) {
                int i = i0 + n; if (i > N - 1) i = N - 1;
                fr[n] = reinterpret_cast<const float4*>(F[b] + i * 32);
            }
            for (int r4 = 0; r4 < 8; ++r4) {
                float4 f0 = fr[0][r4], f1 = fr[1][r4], f2 = fr[2][r4], f3 = fr[3][r4];
                int base = (b * 32 + r4 * 4) * 64 + lane;
                float w0 = wl[base], w1 = wl[base + 64], w2 = wl[base + 128], w3 = wl[base + 192];
                acc[0] += f0.x * w0 + f0.y * w1 + f0.z * w2 + f0.w * w3;
                acc[1] += f1.x * w0 + f1.y * w1 + f1.z * w2 + f1.w * w3;
                acc[2] += f2.x * w0 + f2.y * w1 + f2.z * w2 + f2.w * w3;
                acc[3] += f3.x * w0 + f3.y * w1 + f3.z * w2 + f3.w * w3;
            }
        }
        for (int n = 0; n < 4; ++n) {
            int i = i0 + n;
            if (i < N) {
                float v = acc[n] + bl;
                Z[i * 64 + lane] = 1.0f / (1.0f + expf(-v));
            }
        }
    }
}

// H = (1-Z)*tanh(F @ WcH + bh)  (kept in registers), then xw = H @ gcn_w via shfl.
__global__ __launch_bounds__(256) void k_hxw(
    const float* __restrict__ x, const float* __restrict__ txo1,
    const float* __restrict__ txi1, const float* __restrict__ txo2,
    const float* __restrict__ txi2,
    const float* __restrict__ Wh, const float* __restrict__ bhv,
    const float* __restrict__ gcn_w, const float* __restrict__ Z,
    float* __restrict__ xw, int N) {
    __shared__ float wl[160 * 64];                 // 40 KB
    __shared__ float gw[64 * 64];                  // 16 KB  (total 56 KB <= 64 KB)
    fill_comb_w(wl, Wh, threadIdx.x, blockDim.x);
    for (int idx = threadIdx.x; idx < 64 * 64; idx += blockDim.x) gw[idx] = gcn_w[idx];
    __syncthreads();
    int lane = threadIdx.x & 63;
    int wave = (blockIdx.x * blockDim.x + threadIdx.x) >> 6;
    int nwaves = (gridDim.x * blockDim.x) >> 6;
    float bl = bhv[lane];
    const float* F[5] = {x, txo1, txi1, txo2, txi2};
    for (int i0 = wave * 4; i0 < N; i0 += nwaves * 4) {
        float acc[4] = {0.f, 0.f, 0.f, 0.f};
        for (int b = 0; b < 5; ++b) {
            const float4* fr[4];
            for (int n = 0; n < 4; ++n) {
                int i = i0 + n; if (i > N - 1) i = N - 1;
                fr[n] = reinterpret_cast<const float4*>(F[b] + i * 32);
            }
            for (int r4 = 0; r4 < 8; ++r4) {
                float4 f0 = fr[0][r4], f1 = fr[1][r4], f2 = fr[2][r4], f3 = fr[3][r4];
                int base = (b * 32 + r4 * 4) * 64 + lane;
                float w0 = wl[base], w1 = wl[base + 64], w2 = wl[base + 128], w3 = wl[base + 192];
                acc[0] += f0.x * w0 + f0.y * w1 + f0.z * w2 + f0.w * w3;
                acc[1] += f1.x * w0 + f1.y * w1 + f1.z * w2 + f1.w * w3;
                acc[2] += f2.x * w0 + f2.y * w1 + f2.z * w2 + f2.w * w3;
                acc[3] += f3.x * w0 + f3.y * w1 + f3.z * w2 + f3.w * w3;
            }
        }
        float hv[4];
        for (int n = 0; n < 4; ++n) {
            int i = i0 + n;
            if (i < N) {
                float zv = Z[i * 64 + lane];
                hv[n] = (1.0f - zv) * tanhf(acc[n] + bl);
            } else hv[n] = 0.f;
        }
        float ax[4] = {0.f, 0.f, 0.f, 0.f};
        for (int r = 0; r < 64; ++r) {
            float g = gw[r * 64 + lane];
            ax[0] += __shfl(hv[0], r, 64) * g;
            ax[1] += __shfl(hv[1], r, 64) * g;
            ax[2] += __shfl(hv[2], r, 64) * g;
            ax[3] += __shfl(hv[3], r, 64) * g;
        }
        for (int n = 0; n < 4; ++n) {
            int i = i0 + n;
            if (i < N) xw[i * 64 + lane] = ax[n];
        }
    }
}

// y = dis^2 * xw + gcn_b   (self-loop term; also serves as init for edge atomics)
__global__ void k_gcn_init(const float* __restrict__ dis, const float* __restrict__ xw,
                           const float* __restrict__ gcn_b, float* __restrict__ y, int N) {
    int t = blockIdx.x * blockDim.x + threadIdx.x;
    if (t >= N * 64) return;
    int i = t >> 6, f = t & 63;
    float d = dis[i];
    y[t] = d * d * xw[t] + gcn_b[f];
}

// y[col] += dis[row]*dis[col] * xw[row]
__global__ void k_gcn_edge(const int* __restrict__ row, const int* __restrict__ col,
                           const float* __restrict__ dis, const float* __restrict__ xw,
                           float* __restrict__ y, int E) {
    int t = blockIdx.x * blockDim.x + threadIdx.x;
    if (t >= E * 64) return;
    int e = t >> 6, f = t & 63;
    int r = row[e], c = col[e];
    float nrm = dis[r] * dis[c];
    atomicAdd(&y[c * 64 + f], nrm * xw[r * 64 + f]);
}

// relu in place + per-channel sum/sumsq into stats[0:64]/stats[64:128]
__global__ void k_bn(float* __restrict__ y, float* __restrict__ stats, int N) {
    int f = threadIdx.x & 63;
    int sub = threadIdx.x >> 6;          // 0..3
    float s = 0.f, s2 = 0.f;
    for (int i = blockIdx.x * 4 + sub; i < N; i += gridDim.x * 4) {
        float v = y[i * 64 + f];
        v = v > 0.f ? v : 0.f;
        y[i * 64 + f] = v;
        s += v; s2 += v * v;
    }
    atomicAdd(&stats[f], s);
    atomicAdd(&stats[64 + f], s2);
}

// out[i] = sum_f ((y[i,f]-mean)*istd*gamma + beta) * lw[f] + lb   (wave per node)
__global__ void k_final(const float* __restrict__ y, const float* __restrict__ stats,
                        const float* __restrict__ gma, const float* __restrict__ bta,
                        const float* __restrict__ lw, const float* __restrict__ lb,
                        float* __restrict__ out, int N) {
    int lane = threadIdx.x & 63;
    int wave = (blockIdx.x * blockDim.x + threadIdx.x) >> 6;
    if (wave >= N) return;
    float invN = 1.0f / (float)N;
    float mean = stats[lane] * invN;
    float var  = stats[64 + lane] * invN - mean * mean;   // biased var
    float istd = rsqrtf(var + BN_EPS);
    float v = y[wave * 64 + lane];
    float t = (v - mean) * istd * gma[lane] + bta[lane];
    float p = t * lw[lane];
    for (int off = 32; off > 0; off >>= 1)
        p += __shfl_down(p, off, 64);
    if (lane == 0) out[wave] = p + lb[0];
}

extern "C" void kernel_launch(void* const* d_in, const int* in_sizes, int n_in,
                              void* d_out, int out_size, void* d_ws, size_t ws_size,
                              hipStream_t stream) {
    const float* x     = (const float*)d_in[0];
    const int*   ei    = (const int*)d_in[1];
    const float* ew    = (const float*)d_in[2];
    const float* Wz    = (const float*)d_in[3];
    const float* bz    = (const float*)d_in[4];
    // d_in[5] = Wr, d_in[6] = br : provably unused (H0 == 0)
    const float* Wh    = (const float*)d_in[7];
    const float* bhv   = (const float*)d_in[8];
    const float* gcn_w = (const float*)d_in[9];
    const float* gcn_b = (const float*)d_in[10];
    const float* gma   = (const float*)d_in[11];
    const float* bta   = (const float*)d_in[12];
    const float* lw    = (const float*)d_in[13];
    const float* lb    = (const float*)d_in[14];
    float* out = (float*)d_out;

    const int N = in_sizes[0] / 32;
    const int E = in_sizes[2];
    const int* row = ei;
    const int* col = ei + E;

    // workspace layout (floats). Zero region first, one memset covers it.
    float* ws      = (float*)d_ws;
    float* deg_out = ws;                       // N
    float* deg_in  = ws + N;                   // N
    float* deg_gcn = ws + 2 * N;               // N
    float* stats   = ws + 3 * N;               // 128
    float* txo1    = ws + 3 * N + 128;         // 32N
    float* txi1    = txo1 + 32 * N;            // 32N
    float* txo2    = txi1 + 32 * N;            // 32N
    float* txi2    = txo2 + 32 * N;            // 32N   <- end of zeroed region
    float* w_out   = txi2 + 32 * N;            // E
    float* w_in    = w_out + E;                // E
    float* dis     = w_in + E;                 // N
    float* Zbuf    = dis + N;                  // 64N
    float* xw      = Zbuf + 64 * N;            // 64N
    float* ybuf    = txo1;                     // 64N, overlays txo1+txi1 (dead after k_hxw)

    size_t zero_bytes = (size_t)(131 * N + 128) * sizeof(float);
    hipMemsetAsync(d_ws, 0, zero_bytes, stream);

    int be = (E + 255) / 256;
    k_deg   <<<be, 256, 0, stream>>>(row, col, ew, deg_out, deg_in, deg_gcn, E);
    k_edge_w<<<be, 256, 0, stream>>>(row, col, ew, deg_out, deg_in, w_out, w_in, E);
    k_dis   <<<(N + 255) / 256, 256, 0, stream>>>(deg_gcn, dis, N);

    int bhop = (E * 64 + 255) / 256;
    k_hop<<<bhop, 256, 0, stream>>>(row, col, w_out, w_in, x, x, txo1, txi1, E);
    k_hop<<<bhop, 256, 0, stream>>>(row, col, w_out, w_in, txo1, txi1, txo2, txi2, E);

    k_z  <<<1024, 256, 0, stream>>>(x, txo1, txi1, txo2, txi2, Wz, bz, Zbuf, N);
    k_hxw<<<512, 256, 0, stream>>>(x, txo1, txi1, txo2, txi2, Wh, bhv, gcn_w, Zbuf, xw, N);

    k_gcn_init<<<(N * 64 + 255) / 256, 256, 0, stream>>>(dis, xw, gcn_b, ybuf, N);
    k_gcn_edge<<<(E * 64 + 255) / 256, 256, 0, stream>>>(row, col, dis, xw, ybuf, E);
    k_bn   <<<512, 256, 0, stream>>>(ybuf, stats, N);
    k_final<<<(N + 3) / 4, 256, 0, stream>>>(ybuf, stats, gma, bta, lw, lb, out, N);
}

// Round 2
// 1136.350 us; speedup vs baseline: 2.6330x; 2.6330x over previous
//
#include <hip/hip_runtime.h>
#include <math.h>

// DCRNN (1 step, H0=0) + GCN + BN + Linear for N=50000, F=32, H=64, K=3, E=800000.
//
// Key algebra: H0 == 0  =>  R gate (Wr,br) is unused; hidden half of XH is zero
// through all diffusion hops (propagation is linear), so only W[:, :, :32, :]
// contributes.  F = [x, To1, Ti1, To2, Ti2]  (N x 160),
//   Zpre = F @ WcZ + bz,  Hpre = F @ WcH + bh,  H = (1 - sigmoid(Zpre)) * tanh(Hpre)
// with WcZ rows: [Wz[0,0]+Wz[1,0]; Wz[0,1]; Wz[1,1]; Wz[0,2]; Wz[1,2]] (each [:32,:]).
//
// R2: GEMM kernels rewritten to kill scratch spills (R1: VGPR=256, 485MB spill
// writes). No indexed local arrays; one node per wave; lane = out channel.

#define BN_EPS 1e-5f

// ---------------- degree accumulation (weighted out/in + unweighted gcn) ---------
__global__ void k_deg(const int* __restrict__ row, const int* __restrict__ col,
                      const float* __restrict__ ew,
                      float* __restrict__ deg_out, float* __restrict__ deg_in,
                      float* __restrict__ deg_gcn, int E) {
    int e = blockIdx.x * blockDim.x + threadIdx.x;
    if (e >= E) return;
    float w = ew[e];
    atomicAdd(&deg_out[row[e]], w);
    atomicAdd(&deg_in[col[e]], w);
    atomicAdd(&deg_gcn[col[e]], 1.0f);
}

// per-edge normalized weights w_out = ew/deg_out[row], w_in = ew/deg_in[col]
__global__ void k_edge_w(const int* __restrict__ row, const int* __restrict__ col,
                         const float* __restrict__ ew,
                         const float* __restrict__ deg_out, const float* __restrict__ deg_in,
                         float* __restrict__ w_out, float* __restrict__ w_in, int E) {
    int e = blockIdx.x * blockDim.x + threadIdx.x;
    if (e >= E) return;
    float w  = ew[e];
    float dO = deg_out[row[e]];
    float dI = deg_in[col[e]];
    w_out[e] = dO > 0.f ? w / dO : 0.f;
    w_in[e]  = dI > 0.f ? w / dI : 0.f;
}

// dis[i] = rsqrt(deg_gcn[i] + 1)   (+1 = self loop)
__global__ void k_dis(const float* __restrict__ deg_gcn, float* __restrict__ dis, int N) {
    int i = blockIdx.x * blockDim.x + threadIdx.x;
    if (i >= N) return;
    dis[i] = rsqrtf(deg_gcn[i] + 1.0f);
}

// one diffusion hop, both directions in one launch.
// out-dir: Do[col] += w_out[e]*So[row];  in-dir: Di[row] += w_in[e]*Si[col]
// thread t: f = t&31 (feature), p = t>>5 in [0, 2E)
__global__ void k_hop(const int* __restrict__ row, const int* __restrict__ col,
                      const float* __restrict__ w_out, const float* __restrict__ w_in,
                      const float* __restrict__ So, const float* __restrict__ Si,
                      float* __restrict__ Do, float* __restrict__ Di, int E) {
    int t = blockIdx.x * blockDim.x + threadIdx.x;
    if (t >= E * 64) return;                 // 2 dirs * 32 feats
    int f = t & 31;
    int p = t >> 5;
    if (p < E) {
        int e = p;
        atomicAdd(&Do[col[e] * 32 + f], w_out[e] * So[row[e] * 32 + f]);
    } else {
        int e = p - E;
        atomicAdd(&Di[row[e] * 32 + f], w_in[e] * Si[col[e] * 32 + f]);
    }
}

// fills lds[160*64] with the combined dconv weight built from W (2,3,96,64), rows [:32]
__device__ inline void fill_comb_w(float* lds, const float* __restrict__ W, int tid, int bdim) {
    for (int idx = tid; idx < 160 * 64; idx += bdim) {
        int rr = idx >> 6, c = idx & 63;
        int blk = rr >> 5, r = rr & 31;
        float v;
        if (blk == 0) {
            v = W[r * 64 + c] + W[(3 * 96 + r) * 64 + c];           // W[0,0]+W[1,0]
        } else {
            int k = (blk + 1) >> 1;                                  // 1,1,2,2
            int d = (blk + 1) & 1;                                   // 0,1,0,1
            v = W[((d * 3 + k) * 96 + r) * 64 + c];
        }
        lds[idx] = v;
    }
}

// dot of one 32-float feature row with weight rows [r0..r0+32) column `lane`.
// wl points at the first weight row's base (row-major 160x64 LDS tile).
__device__ inline float dot32(const float* __restrict__ rowp, const float* wl, int lane) {
    const float4* r4p = reinterpret_cast<const float4*>(rowp);
    float acc = 0.f;
#pragma unroll
    for (int r4 = 0; r4 < 8; ++r4) {
        float4 f = r4p[r4];
        const float* w = wl + r4 * 256 + lane;
        acc += f.x * w[0] + f.y * w[64] + f.z * w[128] + f.w * w[192];
    }
    return acc;
}

// Z = sigmoid(F @ WcZ + bz).  wave = 1 node, lane = output channel.
__global__ __launch_bounds__(256) void k_z(
    const float* __restrict__ x, const float* __restrict__ txo1,
    const float* __restrict__ txi1, const float* __restrict__ txo2,
    const float* __restrict__ txi2,
    const float* __restrict__ Wz, const float* __restrict__ bz,
    float* __restrict__ Z, int N) {
    __shared__ float wl[160 * 64];                 // 40 KB
    fill_comb_w(wl, Wz, threadIdx.x, blockDim.x);
    __syncthreads();
    int lane = threadIdx.x & 63;
    int wave = (blockIdx.x * blockDim.x + threadIdx.x) >> 6;
    int nw = (gridDim.x * blockDim.x) >> 6;
    float bl = bz[lane];
    for (int i = wave; i < N; i += nw) {
        float acc = dot32(x    + i * 32, wl,             lane)
                  + dot32(txo1 + i * 32, wl +  32 * 64,  lane)
                  + dot32(txi1 + i * 32, wl +  64 * 64,  lane)
                  + dot32(txo2 + i * 32, wl +  96 * 64,  lane)
                  + dot32(txi2 + i * 32, wl + 128 * 64,  lane);
        float v = acc + bl;
        Z[i * 64 + lane] = 1.0f / (1.0f + expf(-v));
    }
}

// H = (1-Z)*tanh(F @ WcH + bh)  (in registers), then xw = H @ gcn_w via shfl.
__global__ __launch_bounds__(256) void k_hxw(
    const float* __restrict__ x, const float* __restrict__ txo1,
    const float* __restrict__ txi1, const float* __restrict__ txo2,
    const float* __restrict__ txi2,
    const float* __restrict__ Wh, const float* __restrict__ bhv,
    const float* __restrict__ gcn_w, const float* __restrict__ Z,
    float* __restrict__ xw, int N) {
    __shared__ float wl[160 * 64];                 // 40 KB
    __shared__ float gw[64 * 64];                  // 16 KB  (total 56 KB)
    fill_comb_w(wl, Wh, threadIdx.x, blockDim.x);
    for (int idx = threadIdx.x; idx < 64 * 64; idx += blockDim.x) gw[idx] = gcn_w[idx];
    __syncthreads();
    int lane = threadIdx.x & 63;
    int wave = (blockIdx.x * blockDim.x + threadIdx.x) >> 6;
    int nw = (gridDim.x * blockDim.x) >> 6;
    float bl = bhv[lane];
    for (int i = wave; i < N; i += nw) {
        float acc = dot32(x    + i * 32, wl,             lane)
                  + dot32(txo1 + i * 32, wl +  32 * 64,  lane)
                  + dot32(txi1 + i * 32, wl +  64 * 64,  lane)
                  + dot32(txo2 + i * 32, wl +  96 * 64,  lane)
                  + dot32(txi2 + i * 32, wl + 128 * 64,  lane);
        float zv = Z[i * 64 + lane];
        float hv = (1.0f - zv) * tanhf(acc + bl);
        float ax = 0.f;
#pragma unroll
        for (int r = 0; r < 64; ++r) {
            ax += __shfl(hv, r, 64) * gw[r * 64 + lane];
        }
        xw[i * 64 + lane] = ax;
    }
}

// y = dis^2 * xw + gcn_b   (self-loop term; also serves as init for edge atomics)
__global__ void k_gcn_init(const float* __restrict__ dis, const float* __restrict__ xw,
                           const float* __restrict__ gcn_b, float* __restrict__ y, int N) {
    int t = blockIdx.x * blockDim.x + threadIdx.x;
    if (t >= N * 64) return;
    int i = t >> 6, f = t & 63;
    float d = dis[i];
    y[t] = d * d * xw[t] + gcn_b[f];
}

// y[col] += dis[row]*dis[col] * xw[row]
__global__ void k_gcn_edge(const int* __restrict__ row, const int* __restrict__ col,
                           const float* __restrict__ dis, const float* __restrict__ xw,
                           float* __restrict__ y, int E) {
    int t = blockIdx.x * blockDim.x + threadIdx.x;
    if (t >= E * 64) return;
    int e = t >> 6, f = t & 63;
    int r = row[e], c = col[e];
    float nrm = dis[r] * dis[c];
    atomicAdd(&y[c * 64 + f], nrm * xw[r * 64 + f]);
}

// relu in place + per-channel sum/sumsq into stats[0:64]/stats[64:128]
__global__ void k_bn(float* __restrict__ y, float* __restrict__ stats, int N) {
    int f = threadIdx.x & 63;
    int sub = threadIdx.x >> 6;          // 0..3
    float s = 0.f, s2 = 0.f;
    for (int i = blockIdx.x * 4 + sub; i < N; i += gridDim.x * 4) {
        float v = y[i * 64 + f];
        v = v > 0.f ? v : 0.f;
        y[i * 64 + f] = v;
        s += v; s2 += v * v;
    }
    atomicAdd(&stats[f], s);
    atomicAdd(&stats[64 + f], s2);
}

// out[i] = sum_f ((y[i,f]-mean)*istd*gamma + beta) * lw[f] + lb   (wave per node)
__global__ void k_final(const float* __restrict__ y, const float* __restrict__ stats,
                        const float* __restrict__ gma, const float* __restrict__ bta,
                        const float* __restrict__ lw, const float* __restrict__ lb,
                        float* __restrict__ out, int N) {
    int lane = threadIdx.x & 63;
    int wave = (blockIdx.x * blockDim.x + threadIdx.x) >> 6;
    if (wave >= N) return;
    float invN = 1.0f / (float)N;
    float mean = stats[lane] * invN;
    float var  = stats[64 + lane] * invN - mean * mean;   // biased var
    float istd = rsqrtf(var + BN_EPS);
    float v = y[wave * 64 + lane];
    float t = (v - mean) * istd * gma[lane] + bta[lane];
    float p = t * lw[lane];
    for (int off = 32; off > 0; off >>= 1)
        p += __shfl_down(p, off, 64);
    if (lane == 0) out[wave] = p + lb[0];
}

extern "C" void kernel_launch(void* const* d_in, const int* in_sizes, int n_in,
                              void* d_out, int out_size, void* d_ws, size_t ws_size,
                              hipStream_t stream) {
    const float* x     = (const float*)d_in[0];
    const int*   ei    = (const int*)d_in[1];
    const float* ew    = (const float*)d_in[2];
    const float* Wz    = (const float*)d_in[3];
    const float* bz    = (const float*)d_in[4];
    // d_in[5] = Wr, d_in[6] = br : provably unused (H0 == 0)
    const float* Wh    = (const float*)d_in[7];
    const float* bhv   = (const float*)d_in[8];
    const float* gcn_w = (const float*)d_in[9];
    const float* gcn_b = (const float*)d_in[10];
    const float* gma   = (const float*)d_in[11];
    const float* bta   = (const float*)d_in[12];
    const float* lw    = (const float*)d_in[13];
    const float* lb    = (const float*)d_in[14];
    float* out = (float*)d_out;

    const int N = in_sizes[0] / 32;
    const int E = in_sizes[2];
    const int* row = ei;
    const int* col = ei + E;

    // workspace layout (floats). Zero region first, one memset covers it.
    float* ws      = (float*)d_ws;
    float* deg_out = ws;                       // N
    float* deg_in  = ws + N;                   // N
    float* deg_gcn = ws + 2 * N;               // N
    float* stats   = ws + 3 * N;               // 128
    float* txo1    = ws + 3 * N + 128;         // 32N
    float* txi1    = txo1 + 32 * N;            // 32N
    float* txo2    = txi1 + 32 * N;            // 32N
    float* txi2    = txo2 + 32 * N;            // 32N   <- end of zeroed region
    float* w_out   = txi2 + 32 * N;            // E
    float* w_in    = w_out + E;                // E
    float* dis     = w_in + E;                 // N
    float* Zbuf    = dis + N;                  // 64N
    float* xw      = Zbuf + 64 * N;            // 64N
    float* ybuf    = txo1;                     // 64N, overlays txo1+txi1 (dead after k_hxw)

    size_t zero_bytes = (size_t)(131 * N + 128) * sizeof(float);
    hipMemsetAsync(d_ws, 0, zero_bytes, stream);

    int be = (E + 255) / 256;
    k_deg   <<<be, 256, 0, stream>>>(row, col, ew, deg_out, deg_in, deg_gcn, E);
    k_edge_w<<<be, 256, 0, stream>>>(row, col, ew, deg_out, deg_in, w_out, w_in, E);
    k_dis   <<<(N + 255) / 256, 256, 0, stream>>>(deg_gcn, dis, N);

    int bhop = (E * 64 + 255) / 256;
    k_hop<<<bhop, 256, 0, stream>>>(row, col, w_out, w_in, x, x, txo1, txi1, E);
    k_hop<<<bhop, 256, 0, stream>>>(row, col, w_out, w_in, txo1, txi1, txo2, txi2, E);

    k_z  <<<1024, 256, 0, stream>>>(x, txo1, txi1, txo2, txi2, Wz, bz, Zbuf, N);
    k_hxw<<<512, 256, 0, stream>>>(x, txo1, txi1, txo2, txi2, Wh, bhv, gcn_w, Zbuf, xw, N);

    k_gcn_init<<<(N * 64 + 255) / 256, 256, 0, stream>>>(dis, xw, gcn_b, ybuf, N);
    k_gcn_edge<<<(E * 64 + 255) / 256, 256, 0, stream>>>(row, col, dis, xw, ybuf, E);
    k_bn   <<<512, 256, 0, stream>>>(ybuf, stats, N);
    k_final<<<(N + 3) / 4, 256, 0, stream>>>(ybuf, stats, gma, bta, lw, lb, out, N);
}